// Round 2
// baseline (1222.883 us; speedup 1.0000x reference)
//
#include <hip/hip_runtime.h>
#include <stdint.h>

typedef __attribute__((ext_vector_type(8))) short bf16x8;
typedef __attribute__((ext_vector_type(4))) float f32x4;

// ---- LDS layout (ushort element offsets) ----
#define XS_OFF   0                    // Xs  [64][392]
#define QS_OFF   (XS_OFF + 64*392)    // Qs  [2][64][40]
#define KS_OFF   (QS_OFF + 2*64*40)   // Ks  [2][64][40]
#define VT_OFF   (KS_OFF + 2*64*40)   // Vt  [2][32][72]  (v transposed: [d][m])
#define PS_OFF   (VT_OFF + 2*32*72)   // Ps  [2][64][72]
#define OS_OFF   (PS_OFF + 2*64*72)   // Os  [64][392]
#define MS_OFF   (OS_OFF + 64*392)    // mask slice bf16 [49*49] pad 2408
#define BS_OFF   (MS_OFF + 2408)      // bias_table bf16 [169*12]
#define LDS_ELEMS (BS_OFF + 2028)
#define LDS_BYTES (LDS_ELEMS * 2)     // 157,352 B  (<= 160 KiB)

// ---- ws layout (bf16 element offsets) ----
#define W_QKVW   0
#define W_QKVB   442368
#define W_PROJW  443520
#define W_PROJB  590976
#define W_MASK   591360
#define W_BIAS   745024
#define W_ELEMS  747052
#define W_BYTES  (W_ELEMS * 2)

__device__ __forceinline__ float bf2f(unsigned short h) {
  union { unsigned int u; float f; } c; c.u = ((unsigned int)h) << 16; return c.f;
}
__device__ __forceinline__ unsigned short f2bf(float f) {
  union { float f; unsigned int u; } c; c.f = f;
  unsigned int u = c.u;
  u = (u + 0x7FFFu + ((u >> 16) & 1u)) >> 16;
  return (unsigned short)u;
}

// load 8 consecutive f32 and round to bf16x8
__device__ __forceinline__ bf16x8 cvt8(const float* p) {
  f32x4 a = *(const f32x4*)p;
  f32x4 b = *(const f32x4*)(p + 4);
  bf16x8 r;
  r[0] = (short)f2bf(a[0]); r[1] = (short)f2bf(a[1]);
  r[2] = (short)f2bf(a[2]); r[3] = (short)f2bf(a[3]);
  r[4] = (short)f2bf(b[0]); r[5] = (short)f2bf(b[1]);
  r[6] = (short)f2bf(b[2]); r[7] = (short)f2bf(b[3]);
  return r;
}

__global__ void cvt_ws_kernel(const float* __restrict__ qkv_w, const float* __restrict__ qkv_b,
                              const float* __restrict__ proj_w, const float* __restrict__ proj_b,
                              const float* __restrict__ mask, const float* __restrict__ bias_t,
                              unsigned short* __restrict__ ws) {
  const int i = blockIdx.x * blockDim.x + threadIdx.x;
  const int stride = gridDim.x * blockDim.x;
  for (int e = i; e < 442368; e += stride) ws[W_QKVW + e] = f2bf(qkv_w[e]);
  for (int e = i; e < 1152;   e += stride) ws[W_QKVB + e] = f2bf(qkv_b[e]);
  for (int e = i; e < 147456; e += stride) ws[W_PROJW + e] = f2bf(proj_w[e]);
  for (int e = i; e < 384;    e += stride) ws[W_PROJB + e] = f2bf(proj_b[e]);
  for (int e = i; e < 153664; e += stride) ws[W_MASK + e] = f2bf(mask[e]);
  for (int e = i; e < 2028;   e += stride) ws[W_BIAS + e] = f2bf(bias_t[e]);
}

template <bool WS>
__global__ __launch_bounds__(512, 2)
void winattn_kernel(const float* __restrict__ x,
                    const void* __restrict__ maskp,
                    const void* __restrict__ biasp,
                    const void* __restrict__ qkvwp,
                    const void* __restrict__ qkvbp,
                    const void* __restrict__ projwp,
                    const void* __restrict__ projbp,
                    float* __restrict__ out)
{
  extern __shared__ unsigned short sm[];
  unsigned short* Xs = sm + XS_OFF;
  unsigned short* Qs = sm + QS_OFF;
  unsigned short* Ks = sm + KS_OFF;
  unsigned short* Vt = sm + VT_OFF;
  unsigned short* Ps = sm + PS_OFF;
  unsigned short* Os = sm + OS_OFF;
  unsigned short* Ms = sm + MS_OFF;
  unsigned short* Bs = sm + BS_OFF;

  const int b    = blockIdx.x;
  const int tid  = threadIdx.x;
  const int w    = tid >> 6;       // wave 0..7
  const int lane = tid & 63;
  const int l15  = lane & 15;
  const int lg   = lane >> 4;      // 0..3

  // ---------------- phase 0: stage x (f32->bf16), mask slice, bias table ----
  const float* xw = x + b * 18816;                     // 49*384 f32
  for (int e = tid; e < 4704; e += 512) {              // 18816/4 float4 loads
    const int f = e << 2;
    const int r = f / 384;
    const int c = f - r * 384;
    f32x4 v = *(const f32x4*)(xw + f);
    unsigned short* dst = Xs + r * 392 + c;
    dst[0] = f2bf(v[0]); dst[1] = f2bf(v[1]);
    dst[2] = f2bf(v[2]); dst[3] = f2bf(v[3]);
  }
  {
    bf16x8 z = {0,0,0,0,0,0,0,0};
    for (int e = tid; e < 735; e += 512)               // zero pad rows 49..63
      *(bf16x8*)(Xs + 19208 + (e << 3)) = z;           // 49*392 = 19208
  }
  if (WS) {
    const unsigned short* mw = (const unsigned short*)maskp + (b & 63) * 2401;
    for (int e = tid; e < 2401; e += 512) Ms[e] = mw[e];
    const unsigned short* bt = (const unsigned short*)biasp;
    for (int e = tid; e < 2028; e += 512) Bs[e] = bt[e];
  } else {
    const float* mw = (const float*)maskp + (b & 63) * 2401;
    for (int e = tid; e < 2401; e += 512) Ms[e] = f2bf(mw[e]);
    const float* bt = (const float*)biasp;
    for (int e = tid; e < 2028; e += 512) Bs[e] = f2bf(bt[e]);
  }
  __syncthreads();

  // ---------------- head pairs ----------------
  for (int g = 0; g < 6; ++g) {
    // ---- GEMM1: qkv for heads (2g, 2g+1): [64x384] x [384x192] ----
    int t = 6 * w;
    const int tEnd = t + 6;                            // 6 tiles per wave (48 total)
    while (t < tEnd) {
      const int nt  = t >> 2;
      const int hh  = nt / 6;
      const int ntl = nt - hh * 6;
      const int s   = ntl >> 1;                        // 0=q 1=k 2=v
      const int dd  = ((nt & 1) << 4) + l15;           // 0..31 within head
      const int o   = s * 384 + (2 * g + hh) * 32 + dd; // qkv_w row
      bf16x8 Bf[12];
      float biasc;
      if (WS) {
        const unsigned short* wp = (const unsigned short*)qkvwp + o * 384 + lg * 8;
#pragma unroll
        for (int kk = 0; kk < 12; ++kk)
          Bf[kk] = *(const bf16x8*)(wp + kk * 32);
        biasc = bf2f(((const unsigned short*)qkvbp)[o]);
      } else {
        const float* wp = (const float*)qkvwp + o * 384 + lg * 8;
#pragma unroll
        for (int kk = 0; kk < 12; ++kk)
          Bf[kk] = cvt8(wp + kk * 32);
        biasc = ((const float*)qkvbp)[o];
      }
      for (; t < tEnd && (t >> 2) == nt; ++t) {
        const int mt = t & 3;
        f32x4 acc = {0.f, 0.f, 0.f, 0.f};
        const unsigned short* ap = Xs + (mt * 16 + l15) * 392 + lg * 8;
#pragma unroll
        for (int kk = 0; kk < 12; ++kk) {
          bf16x8 Af = *(const bf16x8*)(ap + kk * 32);
          acc = __builtin_amdgcn_mfma_f32_16x16x32_bf16(Af, Bf[kk], acc, 0, 0, 0);
        }
#pragma unroll
        for (int j = 0; j < 4; ++j) {
          const int row = mt * 16 + lg * 4 + j;
          const unsigned short hv = f2bf(acc[j] + biasc);
          if (s == 0)      Qs[hh * 2560 + row * 40 + dd] = hv;
          else if (s == 1) Ks[hh * 2560 + row * 40 + dd] = hv;
          else             Vt[hh * 2304 + dd * 72 + row] = hv;   // transposed
        }
      }
    }
    __syncthreads();

    // ---- QK^T + bias + mask + softmax (wave w: head hh=w>>2, rows mt=w&3) ----
    {
      const int hh   = w >> 2;
      const int mt   = w & 3;
      const int head = 2 * g + hh;
      const unsigned short* qb_ = Qs + hh * 2560;
      const unsigned short* kb_ = Ks + hh * 2560;
      bf16x8 Aq = *(const bf16x8*)(qb_ + (mt * 16 + l15) * 40 + lg * 8);
      f32x4 accs[4];
#pragma unroll
      for (int nt = 0; nt < 4; ++nt) {
        bf16x8 Bk = *(const bf16x8*)(kb_ + (nt * 16 + l15) * 40 + lg * 8);
        f32x4 z = {0.f, 0.f, 0.f, 0.f};
        accs[nt] = __builtin_amdgcn_mfma_f32_16x16x32_bf16(Aq, Bk, z, 0, 0, 0);
      }
#pragma unroll
      for (int j = 0; j < 4; ++j) {
        const int row = mt * 16 + lg * 4 + j;
        float sv[4];
        float vmax = -3e30f;
#pragma unroll
        for (int nt = 0; nt < 4; ++nt) {
          const int col = nt * 16 + l15;
          float v = accs[nt][j] * 0.17677669529663687f;
          if (col < 49) {
            if (row < 49) {
              const int i1 = row / 7, j1 = row - i1 * 7;
              const int i2 = col / 7, j2 = col - i2 * 7;
              const int ridx = (i1 - i2 + 6) * 13 + (j1 - j2 + 6);
              v += bf2f(Ms[row * 49 + col]) + bf2f(Bs[ridx * 12 + head]);
            }
          } else {
            v = -3e30f;                                 // mask out padded cols
          }
          sv[nt] = v;
          vmax = fmaxf(vmax, v);
        }
#pragma unroll
        for (int mm = 1; mm < 16; mm <<= 1)
          vmax = fmaxf(vmax, __shfl_xor(vmax, mm, 64));
        float ssum = 0.f;
#pragma unroll
        for (int nt = 0; nt < 4; ++nt) {
          sv[nt] = __expf(sv[nt] - vmax);
          ssum += sv[nt];
        }
#pragma unroll
        for (int mm = 1; mm < 16; mm <<= 1)
          ssum += __shfl_xor(ssum, mm, 64);
        const float rs = 1.f / ssum;
#pragma unroll
        for (int nt = 0; nt < 4; ++nt) {
          const int col = nt * 16 + l15;
          Ps[hh * 4608 + row * 72 + col] = f2bf(sv[nt] * rs);
        }
      }
    }
    __syncthreads();

    // ---- PV: O = P[64x64] * v[64x32] ----
    {
      const int hh   = w >> 2;
      const int mt   = w & 3;
      const int head = 2 * g + hh;
#pragma unroll
      for (int nt = 0; nt < 2; ++nt) {
        f32x4 acc = {0.f, 0.f, 0.f, 0.f};
#pragma unroll
        for (int kk = 0; kk < 2; ++kk) {
          bf16x8 Ap = *(const bf16x8*)(Ps + hh * 4608 + (mt * 16 + l15) * 72 + kk * 32 + lg * 8);
          bf16x8 Bv = *(const bf16x8*)(Vt + hh * 2304 + (nt * 16 + l15) * 72 + kk * 32 + lg * 8);
          acc = __builtin_amdgcn_mfma_f32_16x16x32_bf16(Ap, Bv, acc, 0, 0, 0);
        }
#pragma unroll
        for (int j = 0; j < 4; ++j) {
          const int row = mt * 16 + lg * 4 + j;
          Os[row * 392 + head * 32 + nt * 16 + l15] = f2bf(acc[j]);
        }
      }
    }
    __syncthreads();
  }

  // ---------------- GEMM2: Os[64x384] * proj_w^T + proj_b ----------------
  for (int nt = 3 * w; nt < 3 * w + 3; ++nt) {
    const int co = nt * 16 + l15;
    bf16x8 Bf[12];
    float pb;
    if (WS) {
      const unsigned short* wp = (const unsigned short*)projwp + co * 384 + lg * 8;
#pragma unroll
      for (int kk = 0; kk < 12; ++kk)
        Bf[kk] = *(const bf16x8*)(wp + kk * 32);
      pb = bf2f(((const unsigned short*)projbp)[co]);
    } else {
      const float* wp = (const float*)projwp + co * 384 + lg * 8;
#pragma unroll
      for (int kk = 0; kk < 12; ++kk)
        Bf[kk] = cvt8(wp + kk * 32);
      pb = ((const float*)projbp)[co];
    }
#pragma unroll
    for (int mt = 0; mt < 4; ++mt) {
      f32x4 acc = {0.f, 0.f, 0.f, 0.f};
      const unsigned short* ap = Os + (mt * 16 + l15) * 392 + lg * 8;
#pragma unroll
      for (int kk = 0; kk < 12; ++kk) {
        bf16x8 Af = *(const bf16x8*)(ap + kk * 32);
        acc = __builtin_amdgcn_mfma_f32_16x16x32_bf16(Af, Bf[kk], acc, 0, 0, 0);
      }
#pragma unroll
      for (int j = 0; j < 4; ++j) {
        const int row = mt * 16 + lg * 4 + j;
        if (row < 49)
          out[b * 18816 + row * 384 + co] = acc[j] + pb;
      }
    }
  }
}

extern "C" void kernel_launch(void* const* d_in, const int* in_sizes, int n_in,
                              void* d_out, int out_size, void* d_ws, size_t ws_size,
                              hipStream_t stream) {
  const float* x      = (const float*)d_in[0];
  const float* mask   = (const float*)d_in[1];
  const float* bias_t = (const float*)d_in[2];
  const float* qkv_w  = (const float*)d_in[3];
  const float* qkv_b  = (const float*)d_in[4];
  const float* proj_w = (const float*)d_in[5];
  const float* proj_b = (const float*)d_in[6];
  float* out = (float*)d_out;

  const bool use_ws = (ws_size >= (size_t)W_BYTES);

  if (use_ws) {
    unsigned short* ws = (unsigned short*)d_ws;
    cvt_ws_kernel<<<dim3(512), dim3(256), 0, stream>>>(
        qkv_w, qkv_b, proj_w, proj_b, mask, bias_t, ws);
    (void)hipFuncSetAttribute((const void*)winattn_kernel<true>,
                              hipFuncAttributeMaxDynamicSharedMemorySize, LDS_BYTES);
    winattn_kernel<true><<<dim3(4096), dim3(512), LDS_BYTES, stream>>>(
        x,
        ws + W_MASK, ws + W_BIAS,
        ws + W_QKVW, ws + W_QKVB,
        ws + W_PROJW, ws + W_PROJB,
        out);
  } else {
    (void)hipFuncSetAttribute((const void*)winattn_kernel<false>,
                              hipFuncAttributeMaxDynamicSharedMemorySize, LDS_BYTES);
    winattn_kernel<false><<<dim3(4096), dim3(512), LDS_BYTES, stream>>>(
        x, mask, bias_t, qkv_w, qkv_b, proj_w, proj_b, out);
  }
}